// Round 17
// baseline (405.192 us; speedup 1.0000x reference)
//
#include <hip/hip_runtime.h>

typedef _Float16 half8 __attribute__((ext_vector_type(8)));
typedef __fp16 fp16x2 __attribute__((ext_vector_type(2)));
typedef unsigned short ushort4v __attribute__((ext_vector_type(4)));
typedef float floatx4 __attribute__((ext_vector_type(4)));
typedef float floatx16 __attribute__((ext_vector_type(16)));

#define MFMA_F16(a, b, c) __builtin_amdgcn_mfma_f32_16x16x32_f16((a), (b), (c), 0, 0, 0)
#define MFMA32(a, b, c) __builtin_amdgcn_mfma_f32_32x32x16_f16((a), (b), (c), 0, 0, 0)

__device__ __forceinline__ unsigned short f2h_bits(float f) {
    union { _Float16 h; unsigned short u; } cv;
    cv.h = (_Float16)f;
    return cv.u;
}

// raw v_exp_f32 (2^x) — OCML exp2f's denormal fixup is dead weight here (R10: -20us)
__device__ __forceinline__ float exp2_hw(float x) {
#if __has_builtin(__builtin_amdgcn_exp2f)
    return __builtin_amdgcn_exp2f(x);
#else
    return exp2f(x);
#endif
}

__device__ __forceinline__ unsigned pkrtz(float a, float b) {
    union { fp16x2 h; unsigned u; } cv;
    cv.h = __builtin_amdgcn_cvt_pkrtz(a, b);
    return cv.u;
}

// permlane32_swap(a,b): r0 = {a.lo32, b.lo32}, r1 = {a.hi32, b.hi32} (lane-half swap)
__device__ __forceinline__ void swap32(unsigned a, unsigned b, int hi32,
                                       unsigned& r0, unsigned& r1) {
#if __has_builtin(__builtin_amdgcn_permlane32_swap)
    auto r = __builtin_amdgcn_permlane32_swap((int)a, (int)b, false, false);
    r0 = (unsigned)r[0];
    r1 = (unsigned)r[1];
#else
    unsigned ax = (unsigned)__shfl_xor((int)a, 32, 64);
    unsigned bx = (unsigned)__shfl_xor((int)b, 32, 64);
    r0 = hi32 ? bx : a;
    r1 = hi32 ? b : ax;
#endif
}

// cross-half max/add: pure VALU (no DS)
__device__ __forceinline__ float xhalf_max(float x) {
#if __has_builtin(__builtin_amdgcn_permlane32_swap)
    auto r = __builtin_amdgcn_permlane32_swap(__float_as_int(x), __float_as_int(x), false, false);
    return fmaxf(__int_as_float(r[0]), __int_as_float(r[1]));
#else
    return fmaxf(x, __shfl_xor(x, 32, 64));
#endif
}
__device__ __forceinline__ float xhalf_add(float x) {
#if __has_builtin(__builtin_amdgcn_permlane32_swap)
    auto r = __builtin_amdgcn_permlane32_swap(__float_as_int(x), __float_as_int(x), false, false);
    return __int_as_float(r[0]) + __int_as_float(r[1]);
#else
    return x + __shfl_xor(x, 32, 64);
#endif
}

__device__ __forceinline__ float bperm_f(int srclane, float v) {
    return __int_as_float(__builtin_amdgcn_ds_bpermute(srclane << 2, __float_as_int(v)));
}

// ---------------------------------------------------------------- converts
__global__ void conv_x_kernel(const float* __restrict__ x, unsigned short* __restrict__ xb) {
    int i = blockIdx.x * 256 + threadIdx.x;          // one float4 per thread, exact grid
    float4 v = ((const float4*)x)[i];
    ushort4 o;
    o.x = f2h_bits(v.x); o.y = f2h_bits(v.y); o.z = f2h_bits(v.z); o.w = f2h_bits(v.w);
    ((ushort4*)xb)[i] = o;
}

// W_kqv [12][768][192] -> Wt [2304][768] f16, Q-columns (c in [64,128)) scaled by 0.125*log2(e)
__global__ void conv_wkqv_kernel(const float* __restrict__ w, unsigned short* __restrict__ wT) {
    int t = blockIdx.x * 256 + threadIdx.x;          // exact grid: 12*192*768
    int d = t % 768;
    int hc = t / 768;
    int h = hc / 192;
    int c = hc - h * 192;
    float v = w[(h * 768 + d) * 192 + c];
    if (c >= 64 && c < 128) v *= 0.18033688011112042f;   // (1/8) * log2(e)
    wT[t] = f2h_bits(v);
}

__global__ void conv_wproj_kernel(const float* __restrict__ w, unsigned short* __restrict__ wb) {
    int i = blockIdx.x * 256 + threadIdx.x;          // exact grid: 768*768/4
    float4 v = ((const float4*)w)[i];
    ushort4 o;
    o.x = f2h_bits(v.x); o.y = f2h_bits(v.y); o.z = f2h_bits(v.z); o.w = f2h_bits(v.w);
    ((ushort4*)wb)[i] = o;
}

// ---------------------------------------------------------------- GEMM  C = A[M,768] * Bt[N,768]^T
// 128x128 tile, BK=64, 4 waves, bijective XCD swizzle (grid%8==0). sEpi aliased onto
// sA/sB (R16: LDS 36.9KB -> up to 4 blocks/CU). EPI==0: LDS-coalesced fragment-major
// epilogue. EPI==1: fp32 out + bias. (verified R16)
template <int EPI>
__global__ __launch_bounds__(256, 3) void gemm_bt_kernel(
    const unsigned short* __restrict__ A, const unsigned short* __restrict__ Bt,
    unsigned short* __restrict__ o_q, unsigned short* __restrict__ o_k,
    unsigned short* __restrict__ o_vt, float* __restrict__ o_f32,
    const float* __restrict__ bias, int Ntiles) {
    __shared__ char smem[EPI == 0 ? 36864 : 32768];  // [sA 16K | sB 16K] / sEpi overlay
    unsigned short* sA = (unsigned short*)smem;
    unsigned short* sB = (unsigned short*)(smem + 16384);
    unsigned short* sEpi = (unsigned short*)smem;    // alias — valid after K-loop + sync
    const int tid = threadIdx.x;
    const int lane = tid & 63;
    const int lo = tid & 15;
    const int hi = (tid >> 4) & 3;
    const int wid = tid >> 6;
    const int wr = wid >> 1;
    const int wc = wid & 1;
    const int cpx = gridDim.x >> 3;                  // grid % 8 == 0 (1152, 384)
    const int blk = (blockIdx.x & 7) * cpx + (blockIdx.x >> 3);  // XCD-contiguous
    const int bm = blk / Ntiles;
    const int bn = blk % Ntiles;
    const size_t rowA0 = (size_t)bm * 128;
    const size_t rowB0 = (size_t)bn * 128;

    const floatx4 ZERO = {0.f, 0.f, 0.f, 0.f};
    floatx4 acc[4][4];
#pragma unroll
    for (int i = 0; i < 4; ++i)
#pragma unroll
        for (int j = 0; j < 4; ++j) acc[i][j] = ZERO;

    const int ldsWaveBase = (tid & 0xC0) << 3;  // wid*512 ushorts (wave-uniform)

    for (int kt = 0; kt < 768; kt += 64) {
        __syncthreads();
#pragma unroll
        for (int it = 0; it < 4; ++it) {
            int g = it * 256 + tid;
            int row = g >> 3;
            int slot = g & 7;
            int koff = kt + ((slot ^ (row & 7)) << 3);  // pre-swizzled global source
            const unsigned short* srcA = A + (rowA0 + row) * 768 + koff;
            const unsigned short* srcB = Bt + (rowB0 + row) * 768 + koff;
            unsigned short* dA = &sA[it * 2048 + ldsWaveBase];
            unsigned short* dB = &sB[it * 2048 + ldsWaveBase];
            __builtin_amdgcn_global_load_lds(
                (const __attribute__((address_space(1))) unsigned int*)srcA,
                (__attribute__((address_space(3))) unsigned int*)dA, 16, 0, 0);
            __builtin_amdgcn_global_load_lds(
                (const __attribute__((address_space(1))) unsigned int*)srcB,
                (__attribute__((address_space(3))) unsigned int*)dB, 16, 0, 0);
        }
        __syncthreads();
#pragma unroll
        for (int kc = 0; kc < 2; ++kc) {
            half8 av[4], bv[4];
#pragma unroll
            for (int mi = 0; mi < 4; ++mi) {
                int row = wr * 64 + mi * 16 + lo;
                av[mi] = *(const half8*)&sA[row * 64 + (((kc * 4 + hi) ^ (lo & 7)) << 3)];
            }
#pragma unroll
            for (int ni = 0; ni < 4; ++ni) {
                int row = wc * 64 + ni * 16 + lo;
                bv[ni] = *(const half8*)&sB[row * 64 + (((kc * 4 + hi) ^ (lo & 7)) << 3)];
            }
#pragma unroll
            for (int mi = 0; mi < 4; ++mi)
#pragma unroll
                for (int ni = 0; ni < 4; ++ni)
                    acc[mi][ni] = MFMA_F16(av[mi], bv[ni], acc[mi][ni]);
        }
    }

    if (EPI == 0) {
        __syncthreads();   // all waves done reading sA/sB before sEpi overlay writes
        const int gnbase = (int)rowB0 + wc * 64;       // 64-aligned -> pure K, Q, or V
        const int h = gnbase / 192;
        const int rem = gnbase - h * 192;              // 0=K, 64=Q, 128=V
        const int gmbase = (int)rowA0 + wr * 64;
        const int b = gmbase >> 12;
        const int t0 = (gmbase & 4095) >> 5;           // first of the wave's 2 k/q tiles
        const int bh = b * 12 + h;
        unsigned short* eb = &sEpi[wid * 64 * 72];     // wave-private, no barrier needed

        if (rem == 128) {
            // V: LDS[dv][gm] (stride 72), packed b64 writes (4 consecutive gm per acc)
#pragma unroll
            for (int mi = 0; mi < 4; ++mi)
#pragma unroll
                for (int ni = 0; ni < 4; ++ni) {
                    ushort4v pk;
                    pk.x = f2h_bits(acc[mi][ni][0]);
                    pk.y = f2h_bits(acc[mi][ni][1]);
                    pk.z = f2h_bits(acc[mi][ni][2]);
                    pk.w = f2h_bits(acc[mi][ni][3]);
                    *(ushort4v*)&eb[(ni * 16 + lo) * 72 + mi * 16 + hi * 4] = pk;
                }
#pragma unroll
            for (int tl = 0; tl < 2; ++tl)
#pragma unroll
                for (int sl = 0; sl < 4; ++sl) {       // sl = dvhi*2 + kin4
                    int dvhi = sl >> 1, kin4 = sl & 1;
                    const half8 v = *(const half8*)&eb[(dvhi * 32 + (lane & 31)) * 72 +
                                                       tl * 32 + kin4 * 16 + (lane >> 5) * 8];
                    *(half8*)&o_vt[(((size_t)bh * 128 + t0 + tl) * 4 + sl) * 512 + lane * 8] = v;
                }
        } else {
            unsigned short* dstbuf = (rem == 0) ? o_k : o_q;
            // K/Q: LDS[gm][d] (stride 72), scalar writes (d contiguous across lanes)
#pragma unroll
            for (int mi = 0; mi < 4; ++mi)
#pragma unroll
                for (int ni = 0; ni < 4; ++ni)
#pragma unroll
                    for (int r = 0; r < 4; ++r)
                        eb[(mi * 16 + hi * 4 + r) * 72 + ni * 16 + lo] =
                            f2h_bits(acc[mi][ni][r]);
#pragma unroll
            for (int tl = 0; tl < 2; ++tl)
#pragma unroll
                for (int ds = 0; ds < 4; ++ds) {
                    const half8 v = *(const half8*)&eb[(tl * 32 + (lane & 31)) * 72 +
                                                       ds * 16 + (lane >> 5) * 8];
                    *(half8*)&dstbuf[(((size_t)bh * 128 + t0 + tl) * 4 + ds) * 512 + lane * 8] = v;
                }
        }
    } else {
#pragma unroll
        for (int mi = 0; mi < 4; ++mi)
#pragma unroll
            for (int ni = 0; ni < 4; ++ni) {
                int gn = (int)rowB0 + wc * 64 + ni * 16 + lo;
                float bs = bias[gn];
#pragma unroll
                for (int r = 0; r < 4; ++r) {
                    int gm = (int)rowA0 + wr * 64 + mi * 16 + hi * 4 + r;
                    o_f32[(size_t)gm * 768 + gn] = acc[mi][ni][r] + bs;
                }
            }
    }
}

// ---------------------------------------------------------------- flash attention (causal)
// R11/R13 base (83us verified x4). R17: K PING-PONG double buffer — body(i) consumes
// kCUR and loads kOTHER for i+2 right after its QK MFMAs (registers just freed; load
// -> use distance = softmax+PV ~1400cy). Manual unroll-by-2, NO copies (R7/R9/R14
// spills all used the copy idiom kfa=kna which doubles the K live range), no
// sched_barrier, no unroll pragma. Peak live ~140 < 170 cap of (128,3).
// Tripwires: WRITE_SIZE >> 20MB = spill -> revert; VGPR > 128 clips occ to 2/SIMD.
__global__ __launch_bounds__(128, 3) void attn_kernel(
    const unsigned short* __restrict__ Qw, const unsigned short* __restrict__ Kw,
    const unsigned short* __restrict__ Vtw, unsigned short* __restrict__ Ow) {
    __shared__ float sM[64 * 35];   // wave1's {m, l, accO0[16], accO1[16]}, stride 35
    const int tid = threadIdx.x;
    const int lane = tid & 63;
    const int wid = tid >> 6;
    const int l31 = lane & 31;
    const int hi32 = lane >> 5;
    const int bh = blockIdx.x % 24;
    const int band = 127 - blockIdx.x / 24;      // heavy blocks dispatch first
    const int b = bh / 12;
    const int h = bh - b * 12;

    const unsigned short* QF = Qw + (size_t)bh * 262144;
    const unsigned short* KF = Kw + (size_t)bh * 262144;
    const unsigned short* VF = Vtw + (size_t)bh * 262144;

    const floatx16 Z16 = {0.f,0.f,0.f,0.f,0.f,0.f,0.f,0.f,0.f,0.f,0.f,0.f,0.f,0.f,0.f,0.f};

    const int q0 = band << 5;
    const int myq = q0 + l31;
    const int nk = (band >> 1) + 1;          // # of 64-key iterations for this band

    half8 qf[4];
#pragma unroll
    for (int ds = 0; ds < 4; ++ds)
        qf[ds] = *(const half8*)&QF[(((size_t)band * 4 + ds) * 64 + lane) * 8];

    floatx16 accO0 = Z16, accO1 = Z16;
    float mI = -1e30f, lI = 0.f;

    half8 kA[8], kB[8];   // ping-pong K buffers: [0..3]=subtile a, [4..7]=subtile b

    auto loadK = [&](int i, half8* dst) {
        const unsigned short* kb = &KF[(size_t)(2 * i) * 2048 + lane * 8];
#pragma unroll
        for (int ds = 0; ds < 4; ++ds) {
            dst[ds] = *(const half8*)(kb + ds * 512);
            dst[4 + ds] = *(const half8*)(kb + 2048 + ds * 512);
        }
    };

    auto body = [&](int i, half8* kcur, half8* knx) {
        const int kt = i << 6;
        // V for this iteration; issued now, consumed after softmax (latency hidden)
        const unsigned short* vb0 = &VF[(size_t)(2 * i) * 2048 + lane * 8];
        half8 vf0[2][2], vf1[2][2];
#pragma unroll
        for (int dt = 0; dt < 2; ++dt)
#pragma unroll
            for (int j = 0; j < 2; ++j) {
                vf0[dt][j] = *(const half8*)(vb0 + (dt * 2 + j) * 512);
                vf1[dt][j] = *(const half8*)(vb0 + 2048 + (dt * 2 + j) * 512);
            }

        // S^T = K x Q for both subtiles (K already in registers)
        floatx16 s0 = Z16, s1 = Z16;
        __builtin_amdgcn_s_setprio(1);
#pragma unroll
        for (int ds = 0; ds < 4; ++ds) s0 = MFMA32(kcur[ds], qf[ds], s0);
#pragma unroll
        for (int ds = 0; ds < 4; ++ds) s1 = MFMA32(kcur[4 + ds], qf[ds], s1);
        __builtin_amdgcn_s_setprio(0);

        // prefetch K(i+2) into the OTHER buffer (kcur's regs are now dead)
        if (i + 2 < nk) loadK(i + 2, knx);

        if (i == nk - 1) {  // diagonal iteration: mask key > myq
#pragma unroll
            for (int r = 0; r < 16; ++r) {
                int crow = (r & 3) + ((r >> 2) << 3) + (hi32 << 2);
                if (kt + crow > myq) s0[r] = -1e30f;
                if (kt + 32 + crow > myq) s1[r] = -1e30f;
            }
        }

        // combined max over 64 keys: 2x-ILP tree + cross-half (VALU permlane)
        float ma[8];
#pragma unroll
        for (int r = 0; r < 8; ++r)
            ma[r] = fmaxf(fmaxf(s0[2 * r], s0[2 * r + 1]),
                          fmaxf(s1[2 * r], s1[2 * r + 1]));
        float mx = fmaxf(fmaxf(fmaxf(ma[0], ma[1]), fmaxf(ma[2], ma[3])),
                         fmaxf(fmaxf(ma[4], ma[5]), fmaxf(ma[6], ma[7])));
        mx = xhalf_max(mx);

        // defer-max: rescale only when some row's max grew past THR=8 (log2 domain)
        if (!__all(mx <= mI + 8.0f)) {
            float mn = fmaxf(mI, mx);
            float sc = exp2_hw(mI - mn);
            mI = mn;
            lI *= sc;
#pragma unroll
            for (int r = 0; r < 16; ++r) {
                int src = (r & 3) + ((r >> 2) << 3) + (hi32 << 2);
                float scb = bperm_f(src, sc);
                accO0[r] *= scb;
                accO1[r] *= scb;
            }
        }

        // P = exp2(s - m) in place (raw v_exp_f32); combined row-sum
#pragma unroll
        for (int r = 0; r < 16; ++r) {
            s0[r] = exp2_hw(s0[r] - mI);
            s1[r] = exp2_hw(s1[r] - mI);
        }
        float sa[8];
#pragma unroll
        for (int r = 0; r < 8; ++r)
            sa[r] = (s0[2 * r] + s0[2 * r + 1]) + (s1[2 * r] + s1[2 * r + 1]);
        float ps = ((sa[0] + sa[1]) + (sa[2] + sa[3])) +
                   ((sa[4] + sa[5]) + (sa[6] + sa[7]));
        lI += xhalf_add(ps);

        // pack subtile 0 -> A-fragments, PV
        {
            unsigned pA0 = pkrtz(s0[0], s0[1]),   pA1 = pkrtz(s0[2], s0[3]);
            unsigned pB0 = pkrtz(s0[4], s0[5]),   pB1 = pkrtz(s0[6], s0[7]);
            unsigned pC0 = pkrtz(s0[8], s0[9]),   pC1 = pkrtz(s0[10], s0[11]);
            unsigned pD0 = pkrtz(s0[12], s0[13]), pD1 = pkrtz(s0[14], s0[15]);
            unsigned w0, w1, w2, w3, u0, u1, u2, u3;
            swap32(pA0, pB0, hi32, w0, w2);
            swap32(pA1, pB1, hi32, w1, w3);
            swap32(pC0, pD0, hi32, u0, u2);
            swap32(pC1, pD1, hi32, u1, u3);
            union { unsigned u[4]; half8 h; } f0, f1;
            f0.u[0] = w0; f0.u[1] = w1; f0.u[2] = w2; f0.u[3] = w3;  // k 0..15
            f1.u[0] = u0; f1.u[1] = u1; f1.u[2] = u2; f1.u[3] = u3;  // k 16..31
            __builtin_amdgcn_s_setprio(1);
            accO0 = MFMA32(f0.h, vf0[0][0], accO0);
            accO0 = MFMA32(f1.h, vf0[0][1], accO0);
            accO1 = MFMA32(f0.h, vf0[1][0], accO1);
            accO1 = MFMA32(f1.h, vf0[1][1], accO1);
            __builtin_amdgcn_s_setprio(0);
        }
        // pack subtile 1 -> A-fragments, PV
        {
            unsigned pA0 = pkrtz(s1[0], s1[1]),   pA1 = pkrtz(s1[2], s1[3]);
            unsigned pB0 = pkrtz(s1[4], s1[5]),   pB1 = pkrtz(s1[6], s1[7]);
            unsigned pC0 = pkrtz(s1[8], s1[9]),   pC1 = pkrtz(s1[10], s1[11]);
            unsigned pD0 = pkrtz(s1[12], s1[13]), pD1 = pkrtz(s1[14], s1[15]);
            unsigned w0, w1, w2, w3, u0, u1, u2, u3;
            swap32(pA0, pB0, hi32, w0, w2);
            swap32(pA1, pB1, hi32, w1, w3);
            swap32(pC0, pD0, hi32, u0, u2);
            swap32(pC1, pD1, hi32, u1, u3);
            union { unsigned u[4]; half8 h; } f0, f1;
            f0.u[0] = w0; f0.u[1] = w1; f0.u[2] = w2; f0.u[3] = w3;  // k 32..47
            f1.u[0] = u0; f1.u[1] = u1; f1.u[2] = u2; f1.u[3] = u3;  // k 48..63
            __builtin_amdgcn_s_setprio(1);
            accO0 = MFMA32(f0.h, vf1[0][0], accO0);
            accO0 = MFMA32(f1.h, vf1[0][1], accO0);
            accO1 = MFMA32(f0.h, vf1[1][0], accO1);
            accO1 = MFMA32(f1.h, vf1[1][1], accO1);
            __builtin_amdgcn_s_setprio(0);
        }
    };

    int i = wid;                         // k-split: wave takes i = wid, wid+2, ...
    if (i < nk) {
        loadK(i, kA);
        for (;;) {
            body(i, kA, kB);
            i += 2;
            if (i >= nk) break;
            body(i, kB, kA);
            i += 2;
            if (i >= nk) break;
        }
    }

    // ---- k-split merge: wave1 publishes partials; wave0 merges + writes O ----
    if (wid == 1) {
        float* dst = &sM[lane * 35];
        dst[0] = mI;
        dst[1] = lI;
#pragma unroll
        for (int r = 0; r < 16; ++r) { dst[2 + r] = accO0[r]; dst[18 + r] = accO1[r]; }
    }
    __syncthreads();
    if (wid == 0) {
        const float* src = &sM[lane * 35];
        float m1 = src[0], l1 = src[1];
        float mstar = fmaxf(mI, m1);
        float sc0 = exp2_hw(mI - mstar);
        float sc1 = exp2_hw(m1 - mstar);
        float lt = lI * sc0 + l1 * sc1;
        float inv = 1.0f / lt;
        float f0 = sc0 * inv, f1 = sc1 * inv;   // per q-row (lane l31, both halves agree)
#pragma unroll
        for (int r = 0; r < 16; ++r) {
            int crow = (r & 3) + ((r >> 2) << 3) + (hi32 << 2);
            float fb0 = bperm_f(crow, f0);
            float fb1 = bperm_f(crow, f1);
            float o0 = accO0[r] * fb0 + src[2 + r] * fb1;
            float o1 = accO1[r] * fb0 + src[18 + r] * fb1;
            int qrow = q0 + crow;
            size_t base = ((size_t)(b * 4096 + qrow)) * 768 + h * 64;
            Ow[base + l31] = f2h_bits(o0);
            Ow[base + 32 + l31] = f2h_bits(o1);
        }
    }
}

// ---------------------------------------------------------------- launch
extern "C" void kernel_launch(void* const* d_in, const int* in_sizes, int n_in,
                              void* d_out, int out_size, void* d_ws, size_t ws_size,
                              hipStream_t stream) {
    const float* x = (const float*)d_in[0];
    const float* wkqv = (const float*)d_in[1];
    const float* wproj = (const float*)d_in[2];
    const float* bproj = (const float*)d_in[3];
    float* out = (float*)d_out;

    char* ws = (char*)d_ws;
    // layout (bytes): xb 12582912 | wkqvT 3538944 | wprojB 1179648 | Q 12582912 | K 12582912 | Vt 12582912
    unsigned short* xb = (unsigned short*)(ws);
    unsigned short* wkqvT = (unsigned short*)(ws + 12582912);
    unsigned short* wprojB = (unsigned short*)(ws + 16121856);
    unsigned short* Qw = (unsigned short*)(ws + 17301504);
    unsigned short* Kw = (unsigned short*)(ws + 29884416);
    unsigned short* Vtw = (unsigned short*)(ws + 42467328);
    unsigned short* Ow = xb;  // xb dead after KQV GEMM; reuse for attention output
    if (ws_size < 55050240) return;

    conv_x_kernel<<<6144, 256, 0, stream>>>(x, xb);
    conv_wkqv_kernel<<<6912, 256, 0, stream>>>(wkqv, wkqvT);
    conv_wproj_kernel<<<576, 256, 0, stream>>>(wproj, wprojB);
    gemm_bt_kernel<0><<<64 * 18, 256, 0, stream>>>(xb, wkqvT, Qw, Kw, Vtw, nullptr, nullptr, 18);
    attn_kernel<<<24 * 128, 128, 0, stream>>>(Qw, Kw, Vtw, Ow);
    gemm_bt_kernel<1><<<64 * 6, 256, 0, stream>>>(Ow, wprojB, nullptr, nullptr, nullptr, out, bproj, 6);
}

// Round 18
// 152.852 us; speedup vs baseline: 2.6509x; 2.6509x over previous
//
#include <hip/hip_runtime.h>

typedef _Float16 half8 __attribute__((ext_vector_type(8)));
typedef __fp16 fp16x2 __attribute__((ext_vector_type(2)));
typedef unsigned short ushort4v __attribute__((ext_vector_type(4)));
typedef float floatx4 __attribute__((ext_vector_type(4)));
typedef float floatx16 __attribute__((ext_vector_type(16)));

#define MFMA_F16(a, b, c) __builtin_amdgcn_mfma_f32_16x16x32_f16((a), (b), (c), 0, 0, 0)
#define MFMA32(a, b, c) __builtin_amdgcn_mfma_f32_32x32x16_f16((a), (b), (c), 0, 0, 0)

__device__ __forceinline__ unsigned short f2h_bits(float f) {
    union { _Float16 h; unsigned short u; } cv;
    cv.h = (_Float16)f;
    return cv.u;
}

// raw v_exp_f32 (2^x) — OCML exp2f's denormal fixup is dead weight here (R10: -20us)
__device__ __forceinline__ float exp2_hw(float x) {
#if __has_builtin(__builtin_amdgcn_exp2f)
    return __builtin_amdgcn_exp2f(x);
#else
    return exp2f(x);
#endif
}

__device__ __forceinline__ unsigned pkrtz(float a, float b) {
    union { fp16x2 h; unsigned u; } cv;
    cv.h = __builtin_amdgcn_cvt_pkrtz(a, b);
    return cv.u;
}

// permlane32_swap(a,b): r0 = {a.lo32, b.lo32}, r1 = {a.hi32, b.hi32} (lane-half swap)
__device__ __forceinline__ void swap32(unsigned a, unsigned b, int hi32,
                                       unsigned& r0, unsigned& r1) {
#if __has_builtin(__builtin_amdgcn_permlane32_swap)
    auto r = __builtin_amdgcn_permlane32_swap((int)a, (int)b, false, false);
    r0 = (unsigned)r[0];
    r1 = (unsigned)r[1];
#else
    unsigned ax = (unsigned)__shfl_xor((int)a, 32, 64);
    unsigned bx = (unsigned)__shfl_xor((int)b, 32, 64);
    r0 = hi32 ? bx : a;
    r1 = hi32 ? b : ax;
#endif
}

// cross-half max/add: pure VALU (no DS)
__device__ __forceinline__ float xhalf_max(float x) {
#if __has_builtin(__builtin_amdgcn_permlane32_swap)
    auto r = __builtin_amdgcn_permlane32_swap(__float_as_int(x), __float_as_int(x), false, false);
    return fmaxf(__int_as_float(r[0]), __int_as_float(r[1]));
#else
    return fmaxf(x, __shfl_xor(x, 32, 64));
#endif
}
__device__ __forceinline__ float xhalf_add(float x) {
#if __has_builtin(__builtin_amdgcn_permlane32_swap)
    auto r = __builtin_amdgcn_permlane32_swap(__float_as_int(x), __float_as_int(x), false, false);
    return __int_as_float(r[0]) + __int_as_float(r[1]);
#else
    return x + __shfl_xor(x, 32, 64);
#endif
}

__device__ __forceinline__ float bperm_f(int srclane, float v) {
    return __int_as_float(__builtin_amdgcn_ds_bpermute(srclane << 2, __float_as_int(v)));
}

// ---------------------------------------------------------------- converts
__global__ void conv_x_kernel(const float* __restrict__ x, unsigned short* __restrict__ xb) {
    int i = blockIdx.x * 256 + threadIdx.x;          // one float4 per thread, exact grid
    float4 v = ((const float4*)x)[i];
    ushort4 o;
    o.x = f2h_bits(v.x); o.y = f2h_bits(v.y); o.z = f2h_bits(v.z); o.w = f2h_bits(v.w);
    ((ushort4*)xb)[i] = o;
}

// W_kqv [12][768][192] -> Wt [2304][768] f16, Q-columns (c in [64,128)) scaled by 0.125*log2(e)
__global__ void conv_wkqv_kernel(const float* __restrict__ w, unsigned short* __restrict__ wT) {
    int t = blockIdx.x * 256 + threadIdx.x;          // exact grid: 12*192*768
    int d = t % 768;
    int hc = t / 768;
    int h = hc / 192;
    int c = hc - h * 192;
    float v = w[(h * 768 + d) * 192 + c];
    if (c >= 64 && c < 128) v *= 0.18033688011112042f;   // (1/8) * log2(e)
    wT[t] = f2h_bits(v);
}

__global__ void conv_wproj_kernel(const float* __restrict__ w, unsigned short* __restrict__ wb) {
    int i = blockIdx.x * 256 + threadIdx.x;          // exact grid: 768*768/4
    float4 v = ((const float4*)w)[i];
    ushort4 o;
    o.x = f2h_bits(v.x); o.y = f2h_bits(v.y); o.z = f2h_bits(v.z); o.w = f2h_bits(v.w);
    ((ushort4*)wb)[i] = o;
}

// ---------------------------------------------------------------- GEMM  C = A[M,768] * Bt[N,768]^T
// BM x 128 tile, BK=64. BM=128: 4 waves (2x2). BM=64: 2 waves (1x2) — used for EPI==1
// so its 768-block grid balances on 256 CUs (was 384 blocks = 2:1 imbalance).
// Bijective XCD swizzle (grid%8==0). sEpi aliased onto sA/sB (R16).
// EPI==0: LDS-coalesced fragment-major epilogue. EPI==1: fp32 out + bias.
template <int EPI, int BM>
__global__ __launch_bounds__(BM == 128 ? 256 : 128, 3) void gemm_bt_kernel(
    const unsigned short* __restrict__ A, const unsigned short* __restrict__ Bt,
    unsigned short* __restrict__ o_q, unsigned short* __restrict__ o_k,
    unsigned short* __restrict__ o_vt, float* __restrict__ o_f32,
    const float* __restrict__ bias, int Ntiles) {
    constexpr int THREADS = (BM == 128) ? 256 : 128;
    __shared__ char smem[EPI == 0 ? 36864 : (BM == 128 ? 32768 : 24576)];
    unsigned short* sA = (unsigned short*)smem;                  // BM x 64
    unsigned short* sB = (unsigned short*)(smem + BM * 128);     // 128 x 64
    unsigned short* sEpi = (unsigned short*)smem;    // alias — valid after K-loop + sync
    const int tid = threadIdx.x;
    const int lane = tid & 63;
    const int lo = tid & 15;
    const int hi = (tid >> 4) & 3;
    const int wid = tid >> 6;
    const int wr = (BM == 128) ? (wid >> 1) : 0;
    const int wc = (BM == 128) ? (wid & 1) : wid;
    const int cpx = gridDim.x >> 3;                  // grid % 8 == 0 (1152, 768)
    const int blk = (blockIdx.x & 7) * cpx + (blockIdx.x >> 3);  // XCD-contiguous
    const int bm = blk / Ntiles;
    const int bn = blk % Ntiles;
    const size_t rowA0 = (size_t)bm * BM;
    const size_t rowB0 = (size_t)bn * 128;

    const floatx4 ZERO = {0.f, 0.f, 0.f, 0.f};
    floatx4 acc[4][4];
#pragma unroll
    for (int i = 0; i < 4; ++i)
#pragma unroll
        for (int j = 0; j < 4; ++j) acc[i][j] = ZERO;

    const int ldsWaveBase = (tid & (THREADS - 64)) << 3;  // wave-uniform (wid*512 ushorts)

    for (int kt = 0; kt < 768; kt += 64) {
        __syncthreads();
        // stage A tile: BM rows x 64 k
#pragma unroll
        for (int it = 0; it < 4; ++it) {
            int g = it * THREADS + tid;              // covers BM*8 slots
            int row = g >> 3;
            int slot = g & 7;
            int koff = kt + ((slot ^ (row & 7)) << 3);  // pre-swizzled global source
            const unsigned short* srcA = A + (rowA0 + row) * 768 + koff;
            unsigned short* dA = &sA[it * (THREADS * 8) + ldsWaveBase];
            __builtin_amdgcn_global_load_lds(
                (const __attribute__((address_space(1))) unsigned int*)srcA,
                (__attribute__((address_space(3))) unsigned int*)dA, 16, 0, 0);
        }
        // stage B tile: 128 rows x 64 k
#pragma unroll
        for (int it = 0; it < (BM == 128 ? 4 : 8); ++it) {
            int g = it * THREADS + tid;              // covers 1024 slots
            int row = g >> 3;
            int slot = g & 7;
            int koff = kt + ((slot ^ (row & 7)) << 3);
            const unsigned short* srcB = Bt + (rowB0 + row) * 768 + koff;
            unsigned short* dB = &sB[it * (THREADS * 8) + ldsWaveBase];
            __builtin_amdgcn_global_load_lds(
                (const __attribute__((address_space(1))) unsigned int*)srcB,
                (__attribute__((address_space(3))) unsigned int*)dB, 16, 0, 0);
        }
        __syncthreads();
#pragma unroll
        for (int kc = 0; kc < 2; ++kc) {
            half8 av[4], bv[4];
#pragma unroll
            for (int mi = 0; mi < 4; ++mi) {
                int row = wr * 64 + mi * 16 + lo;
                av[mi] = *(const half8*)&sA[row * 64 + (((kc * 4 + hi) ^ (lo & 7)) << 3)];
            }
#pragma unroll
            for (int ni = 0; ni < 4; ++ni) {
                int row = wc * 64 + ni * 16 + lo;
                bv[ni] = *(const half8*)&sB[row * 64 + (((kc * 4 + hi) ^ (lo & 7)) << 3)];
            }
#pragma unroll
            for (int mi = 0; mi < 4; ++mi)
#pragma unroll
                for (int ni = 0; ni < 4; ++ni)
                    acc[mi][ni] = MFMA_F16(av[mi], bv[ni], acc[mi][ni]);
        }
    }

    if (EPI == 0) {
        __syncthreads();   // all waves done reading sA/sB before sEpi overlay writes
        const int gnbase = (int)rowB0 + wc * 64;       // 64-aligned -> pure K, Q, or V
        const int h = gnbase / 192;
        const int rem = gnbase - h * 192;              // 0=K, 64=Q, 128=V
        const int gmbase = (int)rowA0 + wr * 64;
        const int b = gmbase >> 12;
        const int t0 = (gmbase & 4095) >> 5;           // first of the wave's 2 k/q tiles
        const int bh = b * 12 + h;
        unsigned short* eb = &sEpi[wid * 64 * 72];     // wave-private, no barrier needed

        if (rem == 128) {
            // V: LDS[dv][gm] (stride 72), packed b64 writes (4 consecutive gm per acc)
#pragma unroll
            for (int mi = 0; mi < 4; ++mi)
#pragma unroll
                for (int ni = 0; ni < 4; ++ni) {
                    ushort4v pk;
                    pk.x = f2h_bits(acc[mi][ni][0]);
                    pk.y = f2h_bits(acc[mi][ni][1]);
                    pk.z = f2h_bits(acc[mi][ni][2]);
                    pk.w = f2h_bits(acc[mi][ni][3]);
                    *(ushort4v*)&eb[(ni * 16 + lo) * 72 + mi * 16 + hi * 4] = pk;
                }
#pragma unroll
            for (int tl = 0; tl < 2; ++tl)
#pragma unroll
                for (int sl = 0; sl < 4; ++sl) {       // sl = dvhi*2 + kin4
                    int dvhi = sl >> 1, kin4 = sl & 1;
                    const half8 v = *(const half8*)&eb[(dvhi * 32 + (lane & 31)) * 72 +
                                                       tl * 32 + kin4 * 16 + (lane >> 5) * 8];
                    *(half8*)&o_vt[(((size_t)bh * 128 + t0 + tl) * 4 + sl) * 512 + lane * 8] = v;
                }
        } else {
            unsigned short* dstbuf = (rem == 0) ? o_k : o_q;
            // K/Q: LDS[gm][d] (stride 72), scalar writes (d contiguous across lanes)
#pragma unroll
            for (int mi = 0; mi < 4; ++mi)
#pragma unroll
                for (int ni = 0; ni < 4; ++ni)
#pragma unroll
                    for (int r = 0; r < 4; ++r)
                        eb[(mi * 16 + hi * 4 + r) * 72 + ni * 16 + lo] =
                            f2h_bits(acc[mi][ni][r]);
#pragma unroll
            for (int tl = 0; tl < 2; ++tl)
#pragma unroll
                for (int ds = 0; ds < 4; ++ds) {
                    const half8 v = *(const half8*)&eb[(tl * 32 + (lane & 31)) * 72 +
                                                       ds * 16 + (lane >> 5) * 8];
                    *(half8*)&dstbuf[(((size_t)bh * 128 + t0 + tl) * 4 + ds) * 512 + lane * 8] = v;
                }
        }
    } else {
#pragma unroll
        for (int mi = 0; mi < 4; ++mi)
#pragma unroll
            for (int ni = 0; ni < 4; ++ni) {
                int gn = (int)rowB0 + wc * 64 + ni * 16 + lo;
                float bs = bias[gn];
#pragma unroll
                for (int r = 0; r < 4; ++r) {
                    int gm = (int)rowA0 + wr * 64 + mi * 16 + hi * 4 + r;
                    o_f32[(size_t)gm * 768 + gn] = acc[mi][ni][r] + bs;
                }
            }
    }
}

// ---------------------------------------------------------------- flash attention (causal)
// EXACT R11/R13/R16 structure (best measured: 83us, VGPR=84, no spill, Occ 27.6%):
// swapped-QK^T 32x32, fragment-major K/Q/V, KBLK=64, permlane reductions, raw
// v_exp_f32, 2-wave k-split + LDS merge, one band per block, heavy-first dispatch.
// (R7/R9/R14/R17 lesson — FINAL: K prefetch spills in every idiom tried; 83us is
// this structure's floor. Do not touch.)
__global__ __launch_bounds__(128, 3) void attn_kernel(
    const unsigned short* __restrict__ Qw, const unsigned short* __restrict__ Kw,
    const unsigned short* __restrict__ Vtw, unsigned short* __restrict__ Ow) {
    __shared__ float sM[64 * 35];   // wave1's {m, l, accO0[16], accO1[16]}, stride 35
    const int tid = threadIdx.x;
    const int lane = tid & 63;
    const int wid = tid >> 6;
    const int l31 = lane & 31;
    const int hi32 = lane >> 5;
    const int bh = blockIdx.x % 24;
    const int band = 127 - blockIdx.x / 24;      // heavy blocks dispatch first
    const int b = bh / 12;
    const int h = bh - b * 12;

    const unsigned short* QF = Qw + (size_t)bh * 262144;
    const unsigned short* KF = Kw + (size_t)bh * 262144;
    const unsigned short* VF = Vtw + (size_t)bh * 262144;

    const floatx16 Z16 = {0.f,0.f,0.f,0.f,0.f,0.f,0.f,0.f,0.f,0.f,0.f,0.f,0.f,0.f,0.f,0.f};

    const int q0 = band << 5;
    const int myq = q0 + l31;
    const int nk = (band >> 1) + 1;          // # of 64-key iterations for this band

    half8 qf[4];
#pragma unroll
    for (int ds = 0; ds < 4; ++ds)
        qf[ds] = *(const half8*)&QF[(((size_t)band * 4 + ds) * 64 + lane) * 8];

    floatx16 accO0 = Z16, accO1 = Z16;
    float mI = -1e30f, lI = 0.f;

    for (int i = wid; i < nk; i += 2) {      // k-split: wave takes i = wid, wid+2, ...
        const int kt = i << 6;
        // K for this iteration (loaded at top — no cross-iteration carry)
        const unsigned short* kb = &KF[(size_t)(2 * i) * 2048 + lane * 8];
        half8 kfa[4], kfb[4];
#pragma unroll
        for (int ds = 0; ds < 4; ++ds) {
            kfa[ds] = *(const half8*)(kb + ds * 512);
            kfb[ds] = *(const half8*)(kb + 2048 + ds * 512);
        }
        // V for this iteration; issued now, consumed after softmax (latency hidden)
        const unsigned short* vb0 = &VF[(size_t)(2 * i) * 2048 + lane * 8];
        half8 vf0[2][2], vf1[2][2];
#pragma unroll
        for (int dt = 0; dt < 2; ++dt)
#pragma unroll
            for (int j = 0; j < 2; ++j) {
                vf0[dt][j] = *(const half8*)(vb0 + (dt * 2 + j) * 512);
                vf1[dt][j] = *(const half8*)(vb0 + 2048 + (dt * 2 + j) * 512);
            }

        // S^T = K x Q for both subtiles
        floatx16 s0 = Z16, s1 = Z16;
        __builtin_amdgcn_s_setprio(1);
#pragma unroll
        for (int ds = 0; ds < 4; ++ds) s0 = MFMA32(kfa[ds], qf[ds], s0);
#pragma unroll
        for (int ds = 0; ds < 4; ++ds) s1 = MFMA32(kfb[ds], qf[ds], s1);
        __builtin_amdgcn_s_setprio(0);

        if (i == nk - 1) {  // diagonal iteration: mask key > myq
#pragma unroll
            for (int r = 0; r < 16; ++r) {
                int crow = (r & 3) + ((r >> 2) << 3) + (hi32 << 2);
                if (kt + crow > myq) s0[r] = -1e30f;
                if (kt + 32 + crow > myq) s1[r] = -1e30f;
            }
        }

        // combined max over 64 keys: 2x-ILP tree + cross-half (VALU permlane)
        float ma[8];
#pragma unroll
        for (int r = 0; r < 8; ++r)
            ma[r] = fmaxf(fmaxf(s0[2 * r], s0[2 * r + 1]),
                          fmaxf(s1[2 * r], s1[2 * r + 1]));
        float mx = fmaxf(fmaxf(fmaxf(ma[0], ma[1]), fmaxf(ma[2], ma[3])),
                         fmaxf(fmaxf(ma[4], ma[5]), fmaxf(ma[6], ma[7])));
        mx = xhalf_max(mx);

        // defer-max: rescale only when some row's max grew past THR=8 (log2 domain)
        if (!__all(mx <= mI + 8.0f)) {
            float mn = fmaxf(mI, mx);
            float sc = exp2_hw(mI - mn);
            mI = mn;
            lI *= sc;
#pragma unroll
            for (int r = 0; r < 16; ++r) {
                int src = (r & 3) + ((r >> 2) << 3) + (hi32 << 2);
                float scb = bperm_f(src, sc);
                accO0[r] *= scb;
                accO1[r] *= scb;
            }
        }

        // P = exp2(s - m) in place (raw v_exp_f32); combined row-sum
#pragma unroll
        for (int r = 0; r < 16; ++r) {
            s0[r] = exp2_hw(s0[r] - mI);
            s1[r] = exp2_hw(s1[r] - mI);
        }
        float sa[8];
#pragma unroll
        for (int r = 0; r < 8; ++r)
            sa[r] = (s0[2 * r] + s0[2 * r + 1]) + (s1[2 * r] + s1[2 * r + 1]);
        float ps = ((sa[0] + sa[1]) + (sa[2] + sa[3])) +
                   ((sa[4] + sa[5]) + (sa[6] + sa[7]));
        lI += xhalf_add(ps);

        // pack subtile 0 -> A-fragments, PV
        {
            unsigned pA0 = pkrtz(s0[0], s0[1]),   pA1 = pkrtz(s0[2], s0[3]);
            unsigned pB0 = pkrtz(s0[4], s0[5]),   pB1 = pkrtz(s0[6], s0[7]);
            unsigned pC0 = pkrtz(s0[8], s0[9]),   pC1 = pkrtz(s0[10], s0[11]);
            unsigned pD0 = pkrtz(s0[12], s0[13]), pD1 = pkrtz(s0[14], s0[15]);
            unsigned w0, w1, w2, w3, u0, u1, u2, u3;
            swap32(pA0, pB0, hi32, w0, w2);
            swap32(pA1, pB1, hi32, w1, w3);
            swap32(pC0, pD0, hi32, u0, u2);
            swap32(pC1, pD1, hi32, u1, u3);
            union { unsigned u[4]; half8 h; } f0, f1;
            f0.u[0] = w0; f0.u[1] = w1; f0.u[2] = w2; f0.u[3] = w3;  // k 0..15
            f1.u[0] = u0; f1.u[1] = u1; f1.u[2] = u2; f1.u[3] = u3;  // k 16..31
            __builtin_amdgcn_s_setprio(1);
            accO0 = MFMA32(f0.h, vf0[0][0], accO0);
            accO0 = MFMA32(f1.h, vf0[0][1], accO0);
            accO1 = MFMA32(f0.h, vf0[1][0], accO1);
            accO1 = MFMA32(f1.h, vf0[1][1], accO1);
            __builtin_amdgcn_s_setprio(0);
        }
        // pack subtile 1 -> A-fragments, PV
        {
            unsigned pA0 = pkrtz(s1[0], s1[1]),   pA1 = pkrtz(s1[2], s1[3]);
            unsigned pB0 = pkrtz(s1[4], s1[5]),   pB1 = pkrtz(s1[6], s1[7]);
            unsigned pC0 = pkrtz(s1[8], s1[9]),   pC1 = pkrtz(s1[10], s1[11]);
            unsigned pD0 = pkrtz(s1[12], s1[13]), pD1 = pkrtz(s1[14], s1[15]);
            unsigned w0, w1, w2, w3, u0, u1, u2, u3;
            swap32(pA0, pB0, hi32, w0, w2);
            swap32(pA1, pB1, hi32, w1, w3);
            swap32(pC0, pD0, hi32, u0, u2);
            swap32(pC1, pD1, hi32, u1, u3);
            union { unsigned u[4]; half8 h; } f0, f1;
            f0.u[0] = w0; f0.u[1] = w1; f0.u[2] = w2; f0.u[3] = w3;  // k 32..47
            f1.u[0] = u0; f1.u[1] = u1; f1.u[2] = u2; f1.u[3] = u3;  // k 48..63
            __builtin_amdgcn_s_setprio(1);
            accO0 = MFMA32(f0.h, vf1[0][0], accO0);
            accO0 = MFMA32(f1.h, vf1[0][1], accO0);
            accO1 = MFMA32(f0.h, vf1[1][0], accO1);
            accO1 = MFMA32(f1.h, vf1[1][1], accO1);
            __builtin_amdgcn_s_setprio(0);
        }
    }

    // ---- k-split merge: wave1 publishes partials; wave0 merges + writes O ----
    if (wid == 1) {
        float* dst = &sM[lane * 35];
        dst[0] = mI;
        dst[1] = lI;
#pragma unroll
        for (int r = 0; r < 16; ++r) { dst[2 + r] = accO0[r]; dst[18 + r] = accO1[r]; }
    }
    __syncthreads();
    if (wid == 0) {
        const float* src = &sM[lane * 35];
        float m1 = src[0], l1 = src[1];
        float mstar = fmaxf(mI, m1);
        float sc0 = exp2_hw(mI - mstar);
        float sc1 = exp2_hw(m1 - mstar);
        float lt = lI * sc0 + l1 * sc1;
        float inv = 1.0f / lt;
        float f0 = sc0 * inv, f1 = sc1 * inv;   // per q-row (lane l31, both halves agree)
#pragma unroll
        for (int r = 0; r < 16; ++r) {
            int crow = (r & 3) + ((r >> 2) << 3) + (hi32 << 2);
            float fb0 = bperm_f(crow, f0);
            float fb1 = bperm_f(crow, f1);
            float o0 = accO0[r] * fb0 + src[2 + r] * fb1;
            float o1 = accO1[r] * fb0 + src[18 + r] * fb1;
            int qrow = q0 + crow;
            size_t base = ((size_t)(b * 4096 + qrow)) * 768 + h * 64;
            Ow[base + l31] = f2h_bits(o0);
            Ow[base + 32 + l31] = f2h_bits(o1);
        }
    }
}

// ---------------------------------------------------------------- launch
extern "C" void kernel_launch(void* const* d_in, const int* in_sizes, int n_in,
                              void* d_out, int out_size, void* d_ws, size_t ws_size,
                              hipStream_t stream) {
    const float* x = (const float*)d_in[0];
    const float* wkqv = (const float*)d_in[1];
    const float* wproj = (const float*)d_in[2];
    const float* bproj = (const float*)d_in[3];
    float* out = (float*)d_out;

    char* ws = (char*)d_ws;
    // layout (bytes): xb 12582912 | wkqvT 3538944 | wprojB 1179648 | Q 12582912 | K 12582912 | Vt 12582912
    unsigned short* xb = (unsigned short*)(ws);
    unsigned short* wkqvT = (unsigned short*)(ws + 12582912);
    unsigned short* wprojB = (unsigned short*)(ws + 16121856);
    unsigned short* Qw = (unsigned short*)(ws + 17301504);
    unsigned short* Kw = (unsigned short*)(ws + 29884416);
    unsigned short* Vtw = (unsigned short*)(ws + 42467328);
    unsigned short* Ow = xb;  // xb dead after KQV GEMM; reuse for attention output
    if (ws_size < 55050240) return;

    conv_x_kernel<<<6144, 256, 0, stream>>>(x, xb);
    conv_wkqv_kernel<<<6912, 256, 0, stream>>>(wkqv, wkqvT);
    conv_wproj_kernel<<<576, 256, 0, stream>>>(wproj, wprojB);
    gemm_bt_kernel<0, 128><<<64 * 18, 256, 0, stream>>>(xb, wkqvT, Qw, Kw, Vtw, nullptr, nullptr, 18);
    attn_kernel<<<24 * 128, 128, 0, stream>>>(Qw, Kw, Vtw, Ow);
    gemm_bt_kernel<1, 64><<<128 * 6, 128, 0, stream>>>(Ow, wprojB, nullptr, nullptr, nullptr, out, bproj, 6);
}

// Round 19
// 148.773 us; speedup vs baseline: 2.7236x; 1.0274x over previous
//
#include <hip/hip_runtime.h>

typedef _Float16 half8 __attribute__((ext_vector_type(8)));
typedef __fp16 fp16x2 __attribute__((ext_vector_type(2)));
typedef unsigned short ushort4v __attribute__((ext_vector_type(4)));
typedef float floatx4 __attribute__((ext_vector_type(4)));
typedef float floatx16 __attribute__((ext_vector_type(16)));

#define MFMA_F16(a, b, c) __builtin_amdgcn_mfma_f32_16x16x32_f16((a), (b), (c), 0, 0, 0)
#define MFMA32(a, b, c) __builtin_amdgcn_mfma_f32_32x32x16_f16((a), (b), (c), 0, 0, 0)

__device__ __forceinline__ unsigned short f2h_bits(float f) {
    union { _Float16 h; unsigned short u; } cv;
    cv.h = (_Float16)f;
    return cv.u;
}

// raw v_exp_f32 (2^x) — OCML exp2f's denormal fixup is dead weight here (R10: -20us)
__device__ __forceinline__ float exp2_hw(float x) {
#if __has_builtin(__builtin_amdgcn_exp2f)
    return __builtin_amdgcn_exp2f(x);
#else
    return exp2f(x);
#endif
}

__device__ __forceinline__ unsigned pkrtz(float a, float b) {
    union { fp16x2 h; unsigned u; } cv;
    cv.h = __builtin_amdgcn_cvt_pkrtz(a, b);
    return cv.u;
}

// permlane32_swap(a,b): r0 = {a.lo32, b.lo32}, r1 = {a.hi32, b.hi32} (lane-half swap)
__device__ __forceinline__ void swap32(unsigned a, unsigned b, int hi32,
                                       unsigned& r0, unsigned& r1) {
#if __has_builtin(__builtin_amdgcn_permlane32_swap)
    auto r = __builtin_amdgcn_permlane32_swap((int)a, (int)b, false, false);
    r0 = (unsigned)r[0];
    r1 = (unsigned)r[1];
#else
    unsigned ax = (unsigned)__shfl_xor((int)a, 32, 64);
    unsigned bx = (unsigned)__shfl_xor((int)b, 32, 64);
    r0 = hi32 ? bx : a;
    r1 = hi32 ? b : ax;
#endif
}

// cross-half max/add: pure VALU (no DS)
__device__ __forceinline__ float xhalf_max(float x) {
#if __has_builtin(__builtin_amdgcn_permlane32_swap)
    auto r = __builtin_amdgcn_permlane32_swap(__float_as_int(x), __float_as_int(x), false, false);
    return fmaxf(__int_as_float(r[0]), __int_as_float(r[1]));
#else
    return fmaxf(x, __shfl_xor(x, 32, 64));
#endif
}
__device__ __forceinline__ float xhalf_add(float x) {
#if __has_builtin(__builtin_amdgcn_permlane32_swap)
    auto r = __builtin_amdgcn_permlane32_swap(__float_as_int(x), __float_as_int(x), false, false);
    return __int_as_float(r[0]) + __int_as_float(r[1]);
#else
    return x + __shfl_xor(x, 32, 64);
#endif
}

__device__ __forceinline__ float bperm_f(int srclane, float v) {
    return __int_as_float(__builtin_amdgcn_ds_bpermute(srclane << 2, __float_as_int(v)));
}

// ---------------------------------------------------------------- fused converts
// One dispatch replaces conv_x (6144 blocks) + conv_wkqv (6912) + conv_wproj (576):
// saves 2 kernel boundaries; branch is blockIdx-uniform (no divergence).
__global__ void conv_all_kernel(const float* __restrict__ x, unsigned short* __restrict__ xb,
                                const float* __restrict__ wkqv, unsigned short* __restrict__ wT,
                                const float* __restrict__ wproj, unsigned short* __restrict__ wb) {
    const int blk = blockIdx.x;
    if (blk < 6144) {                     // x: [2,4096,768] fp32 -> f16, float4/thread
        int i = blk * 256 + threadIdx.x;
        float4 v = ((const float4*)x)[i];
        ushort4 o;
        o.x = f2h_bits(v.x); o.y = f2h_bits(v.y); o.z = f2h_bits(v.z); o.w = f2h_bits(v.w);
        ((ushort4*)xb)[i] = o;
    } else if (blk < 13056) {             // W_kqv [12][768][192] -> Wt [2304][768]
        int t = (blk - 6144) * 256 + threadIdx.x;   // exact: 12*192*768
        int d = t % 768;
        int hc = t / 768;
        int h = hc / 192;
        int c = hc - h * 192;
        float v = wkqv[(h * 768 + d) * 192 + c];
        if (c >= 64 && c < 128) v *= 0.18033688011112042f;   // (1/8) * log2(e)
        wT[t] = f2h_bits(v);
    } else {                              // W_proj [768][768] fp32 -> f16
        int i = (blk - 13056) * 256 + threadIdx.x;  // exact: 768*768/4
        float4 v = ((const float4*)wproj)[i];
        ushort4 o;
        o.x = f2h_bits(v.x); o.y = f2h_bits(v.y); o.z = f2h_bits(v.z); o.w = f2h_bits(v.w);
        ((ushort4*)wb)[i] = o;
    }
}

// ---------------------------------------------------------------- GEMM  C = A[M,768] * Bt[N,768]^T
// BM x 128 tile, BK=64. BM=128: 4 waves (2x2). BM=64: 2 waves (1x2) — used for EPI==1
// so its 768-block grid balances on 256 CUs. Bijective XCD swizzle (grid%8==0).
// sEpi aliased onto sA/sB (R16). EPI==0: LDS-coalesced fragment-major epilogue.
// EPI==1: fp32 out + bias. (verified R16-R18)
template <int EPI, int BM>
__global__ __launch_bounds__(BM == 128 ? 256 : 128, 3) void gemm_bt_kernel(
    const unsigned short* __restrict__ A, const unsigned short* __restrict__ Bt,
    unsigned short* __restrict__ o_q, unsigned short* __restrict__ o_k,
    unsigned short* __restrict__ o_vt, float* __restrict__ o_f32,
    const float* __restrict__ bias, int Ntiles) {
    constexpr int THREADS = (BM == 128) ? 256 : 128;
    __shared__ char smem[EPI == 0 ? 36864 : (BM == 128 ? 32768 : 24576)];
    unsigned short* sA = (unsigned short*)smem;                  // BM x 64
    unsigned short* sB = (unsigned short*)(smem + BM * 128);     // 128 x 64
    unsigned short* sEpi = (unsigned short*)smem;    // alias — valid after K-loop + sync
    const int tid = threadIdx.x;
    const int lane = tid & 63;
    const int lo = tid & 15;
    const int hi = (tid >> 4) & 3;
    const int wid = tid >> 6;
    const int wr = (BM == 128) ? (wid >> 1) : 0;
    const int wc = (BM == 128) ? (wid & 1) : wid;
    const int cpx = gridDim.x >> 3;                  // grid % 8 == 0 (1152, 768)
    const int blk = (blockIdx.x & 7) * cpx + (blockIdx.x >> 3);  // XCD-contiguous
    const int bm = blk / Ntiles;
    const int bn = blk % Ntiles;
    const size_t rowA0 = (size_t)bm * BM;
    const size_t rowB0 = (size_t)bn * 128;

    const floatx4 ZERO = {0.f, 0.f, 0.f, 0.f};
    floatx4 acc[4][4];
#pragma unroll
    for (int i = 0; i < 4; ++i)
#pragma unroll
        for (int j = 0; j < 4; ++j) acc[i][j] = ZERO;

    const int ldsWaveBase = (tid & (THREADS - 64)) << 3;  // wave-uniform (wid*512 ushorts)

    for (int kt = 0; kt < 768; kt += 64) {
        __syncthreads();
        // stage A tile: BM rows x 64 k
#pragma unroll
        for (int it = 0; it < 4; ++it) {
            int g = it * THREADS + tid;              // covers BM*8 slots
            int row = g >> 3;
            int slot = g & 7;
            int koff = kt + ((slot ^ (row & 7)) << 3);  // pre-swizzled global source
            const unsigned short* srcA = A + (rowA0 + row) * 768 + koff;
            unsigned short* dA = &sA[it * (THREADS * 8) + ldsWaveBase];
            __builtin_amdgcn_global_load_lds(
                (const __attribute__((address_space(1))) unsigned int*)srcA,
                (__attribute__((address_space(3))) unsigned int*)dA, 16, 0, 0);
        }
        // stage B tile: 128 rows x 64 k
#pragma unroll
        for (int it = 0; it < (BM == 128 ? 4 : 8); ++it) {
            int g = it * THREADS + tid;              // covers 1024 slots
            int row = g >> 3;
            int slot = g & 7;
            int koff = kt + ((slot ^ (row & 7)) << 3);
            const unsigned short* srcB = Bt + (rowB0 + row) * 768 + koff;
            unsigned short* dB = &sB[it * (THREADS * 8) + ldsWaveBase];
            __builtin_amdgcn_global_load_lds(
                (const __attribute__((address_space(1))) unsigned int*)srcB,
                (__attribute__((address_space(3))) unsigned int*)dB, 16, 0, 0);
        }
        __syncthreads();
#pragma unroll
        for (int kc = 0; kc < 2; ++kc) {
            half8 av[4], bv[4];
#pragma unroll
            for (int mi = 0; mi < 4; ++mi) {
                int row = wr * 64 + mi * 16 + lo;
                av[mi] = *(const half8*)&sA[row * 64 + (((kc * 4 + hi) ^ (lo & 7)) << 3)];
            }
#pragma unroll
            for (int ni = 0; ni < 4; ++ni) {
                int row = wc * 64 + ni * 16 + lo;
                bv[ni] = *(const half8*)&sB[row * 64 + (((kc * 4 + hi) ^ (lo & 7)) << 3)];
            }
#pragma unroll
            for (int mi = 0; mi < 4; ++mi)
#pragma unroll
                for (int ni = 0; ni < 4; ++ni)
                    acc[mi][ni] = MFMA_F16(av[mi], bv[ni], acc[mi][ni]);
        }
    }

    if (EPI == 0) {
        __syncthreads();   // all waves done reading sA/sB before sEpi overlay writes
        const int gnbase = (int)rowB0 + wc * 64;       // 64-aligned -> pure K, Q, or V
        const int h = gnbase / 192;
        const int rem = gnbase - h * 192;              // 0=K, 64=Q, 128=V
        const int gmbase = (int)rowA0 + wr * 64;
        const int b = gmbase >> 12;
        const int t0 = (gmbase & 4095) >> 5;           // first of the wave's 2 k/q tiles
        const int bh = b * 12 + h;
        unsigned short* eb = &sEpi[wid * 64 * 72];     // wave-private, no barrier needed

        if (rem == 128) {
            // V: LDS[dv][gm] (stride 72), packed b64 writes (4 consecutive gm per acc)
#pragma unroll
            for (int mi = 0; mi < 4; ++mi)
#pragma unroll
                for (int ni = 0; ni < 4; ++ni) {
                    ushort4v pk;
                    pk.x = f2h_bits(acc[mi][ni][0]);
                    pk.y = f2h_bits(acc[mi][ni][1]);
                    pk.z = f2h_bits(acc[mi][ni][2]);
                    pk.w = f2h_bits(acc[mi][ni][3]);
                    *(ushort4v*)&eb[(ni * 16 + lo) * 72 + mi * 16 + hi * 4] = pk;
                }
#pragma unroll
            for (int tl = 0; tl < 2; ++tl)
#pragma unroll
                for (int sl = 0; sl < 4; ++sl) {       // sl = dvhi*2 + kin4
                    int dvhi = sl >> 1, kin4 = sl & 1;
                    const half8 v = *(const half8*)&eb[(dvhi * 32 + (lane & 31)) * 72 +
                                                       tl * 32 + kin4 * 16 + (lane >> 5) * 8];
                    *(half8*)&o_vt[(((size_t)bh * 128 + t0 + tl) * 4 + sl) * 512 + lane * 8] = v;
                }
        } else {
            unsigned short* dstbuf = (rem == 0) ? o_k : o_q;
            // K/Q: LDS[gm][d] (stride 72), scalar writes (d contiguous across lanes)
#pragma unroll
            for (int mi = 0; mi < 4; ++mi)
#pragma unroll
                for (int ni = 0; ni < 4; ++ni)
#pragma unroll
                    for (int r = 0; r < 4; ++r)
                        eb[(mi * 16 + hi * 4 + r) * 72 + ni * 16 + lo] =
                            f2h_bits(acc[mi][ni][r]);
#pragma unroll
            for (int tl = 0; tl < 2; ++tl)
#pragma unroll
                for (int ds = 0; ds < 4; ++ds) {
                    const half8 v = *(const half8*)&eb[(tl * 32 + (lane & 31)) * 72 +
                                                       ds * 16 + (lane >> 5) * 8];
                    *(half8*)&dstbuf[(((size_t)bh * 128 + t0 + tl) * 4 + ds) * 512 + lane * 8] = v;
                }
        }
    } else {
#pragma unroll
        for (int mi = 0; mi < 4; ++mi)
#pragma unroll
            for (int ni = 0; ni < 4; ++ni) {
                int gn = (int)rowB0 + wc * 64 + ni * 16 + lo;
                float bs = bias[gn];
#pragma unroll
                for (int r = 0; r < 4; ++r) {
                    int gm = (int)rowA0 + wr * 64 + mi * 16 + hi * 4 + r;
                    o_f32[(size_t)gm * 768 + gn] = acc[mi][ni][r] + bs;
                }
            }
    }
}

// ---------------------------------------------------------------- flash attention (causal)
// EXACT R11/R13/R16 structure (best measured: 83us, VGPR=84, no spill, Occ 27.6%):
// swapped-QK^T 32x32, fragment-major K/Q/V, KBLK=64, permlane reductions, raw
// v_exp_f32, 2-wave k-split + LDS merge, one band per block, heavy-first dispatch.
// (R7/R9/R14/R17 lesson — FINAL: K prefetch spills in every idiom tried; 83us is
// this structure's floor. Do not touch.)
__global__ __launch_bounds__(128, 3) void attn_kernel(
    const unsigned short* __restrict__ Qw, const unsigned short* __restrict__ Kw,
    const unsigned short* __restrict__ Vtw, unsigned short* __restrict__ Ow) {
    __shared__ float sM[64 * 35];   // wave1's {m, l, accO0[16], accO1[16]}, stride 35
    const int tid = threadIdx.x;
    const int lane = tid & 63;
    const int wid = tid >> 6;
    const int l31 = lane & 31;
    const int hi32 = lane >> 5;
    const int bh = blockIdx.x % 24;
    const int band = 127 - blockIdx.x / 24;      // heavy blocks dispatch first
    const int b = bh / 12;
    const int h = bh - b * 12;

    const unsigned short* QF = Qw + (size_t)bh * 262144;
    const unsigned short* KF = Kw + (size_t)bh * 262144;
    const unsigned short* VF = Vtw + (size_t)bh * 262144;

    const floatx16 Z16 = {0.f,0.f,0.f,0.f,0.f,0.f,0.f,0.f,0.f,0.f,0.f,0.f,0.f,0.f,0.f,0.f};

    const int q0 = band << 5;
    const int myq = q0 + l31;
    const int nk = (band >> 1) + 1;          // # of 64-key iterations for this band

    half8 qf[4];
#pragma unroll
    for (int ds = 0; ds < 4; ++ds)
        qf[ds] = *(const half8*)&QF[(((size_t)band * 4 + ds) * 64 + lane) * 8];

    floatx16 accO0 = Z16, accO1 = Z16;
    float mI = -1e30f, lI = 0.f;

    for (int i = wid; i < nk; i += 2) {      // k-split: wave takes i = wid, wid+2, ...
        const int kt = i << 6;
        // K for this iteration (loaded at top — no cross-iteration carry)
        const unsigned short* kb = &KF[(size_t)(2 * i) * 2048 + lane * 8];
        half8 kfa[4], kfb[4];
#pragma unroll
        for (int ds = 0; ds < 4; ++ds) {
            kfa[ds] = *(const half8*)(kb + ds * 512);
            kfb[ds] = *(const half8*)(kb + 2048 + ds * 512);
        }
        // V for this iteration; issued now, consumed after softmax (latency hidden)
        const unsigned short* vb0 = &VF[(size_t)(2 * i) * 2048 + lane * 8];
        half8 vf0[2][2], vf1[2][2];
#pragma unroll
        for (int dt = 0; dt < 2; ++dt)
#pragma unroll
            for (int j = 0; j < 2; ++j) {
                vf0[dt][j] = *(const half8*)(vb0 + (dt * 2 + j) * 512);
                vf1[dt][j] = *(const half8*)(vb0 + 2048 + (dt * 2 + j) * 512);
            }

        // S^T = K x Q for both subtiles
        floatx16 s0 = Z16, s1 = Z16;
        __builtin_amdgcn_s_setprio(1);
#pragma unroll
        for (int ds = 0; ds < 4; ++ds) s0 = MFMA32(kfa[ds], qf[ds], s0);
#pragma unroll
        for (int ds = 0; ds < 4; ++ds) s1 = MFMA32(kfb[ds], qf[ds], s1);
        __builtin_amdgcn_s_setprio(0);

        if (i == nk - 1) {  // diagonal iteration: mask key > myq
#pragma unroll
            for (int r = 0; r < 16; ++r) {
                int crow = (r & 3) + ((r >> 2) << 3) + (hi32 << 2);
                if (kt + crow > myq) s0[r] = -1e30f;
                if (kt + 32 + crow > myq) s1[r] = -1e30f;
            }
        }

        // combined max over 64 keys: 2x-ILP tree + cross-half (VALU permlane)
        float ma[8];
#pragma unroll
        for (int r = 0; r < 8; ++r)
            ma[r] = fmaxf(fmaxf(s0[2 * r], s0[2 * r + 1]),
                          fmaxf(s1[2 * r], s1[2 * r + 1]));
        float mx = fmaxf(fmaxf(fmaxf(ma[0], ma[1]), fmaxf(ma[2], ma[3])),
                         fmaxf(fmaxf(ma[4], ma[5]), fmaxf(ma[6], ma[7])));
        mx = xhalf_max(mx);

        // defer-max: rescale only when some row's max grew past THR=8 (log2 domain)
        if (!__all(mx <= mI + 8.0f)) {
            float mn = fmaxf(mI, mx);
            float sc = exp2_hw(mI - mn);
            mI = mn;
            lI *= sc;
#pragma unroll
            for (int r = 0; r < 16; ++r) {
                int src = (r & 3) + ((r >> 2) << 3) + (hi32 << 2);
                float scb = bperm_f(src, sc);
                accO0[r] *= scb;
                accO1[r] *= scb;
            }
        }

        // P = exp2(s - m) in place (raw v_exp_f32); combined row-sum
#pragma unroll
        for (int r = 0; r < 16; ++r) {
            s0[r] = exp2_hw(s0[r] - mI);
            s1[r] = exp2_hw(s1[r] - mI);
        }
        float sa[8];
#pragma unroll
        for (int r = 0; r < 8; ++r)
            sa[r] = (s0[2 * r] + s0[2 * r + 1]) + (s1[2 * r] + s1[2 * r + 1]);
        float ps = ((sa[0] + sa[1]) + (sa[2] + sa[3])) +
                   ((sa[4] + sa[5]) + (sa[6] + sa[7]));
        lI += xhalf_add(ps);

        // pack subtile 0 -> A-fragments, PV
        {
            unsigned pA0 = pkrtz(s0[0], s0[1]),   pA1 = pkrtz(s0[2], s0[3]);
            unsigned pB0 = pkrtz(s0[4], s0[5]),   pB1 = pkrtz(s0[6], s0[7]);
            unsigned pC0 = pkrtz(s0[8], s0[9]),   pC1 = pkrtz(s0[10], s0[11]);
            unsigned pD0 = pkrtz(s0[12], s0[13]), pD1 = pkrtz(s0[14], s0[15]);
            unsigned w0, w1, w2, w3, u0, u1, u2, u3;
            swap32(pA0, pB0, hi32, w0, w2);
            swap32(pA1, pB1, hi32, w1, w3);
            swap32(pC0, pD0, hi32, u0, u2);
            swap32(pC1, pD1, hi32, u1, u3);
            union { unsigned u[4]; half8 h; } f0, f1;
            f0.u[0] = w0; f0.u[1] = w1; f0.u[2] = w2; f0.u[3] = w3;  // k 0..15
            f1.u[0] = u0; f1.u[1] = u1; f1.u[2] = u2; f1.u[3] = u3;  // k 16..31
            __builtin_amdgcn_s_setprio(1);
            accO0 = MFMA32(f0.h, vf0[0][0], accO0);
            accO0 = MFMA32(f1.h, vf0[0][1], accO0);
            accO1 = MFMA32(f0.h, vf0[1][0], accO1);
            accO1 = MFMA32(f1.h, vf0[1][1], accO1);
            __builtin_amdgcn_s_setprio(0);
        }
        // pack subtile 1 -> A-fragments, PV
        {
            unsigned pA0 = pkrtz(s1[0], s1[1]),   pA1 = pkrtz(s1[2], s1[3]);
            unsigned pB0 = pkrtz(s1[4], s1[5]),   pB1 = pkrtz(s1[6], s1[7]);
            unsigned pC0 = pkrtz(s1[8], s1[9]),   pC1 = pkrtz(s1[10], s1[11]);
            unsigned pD0 = pkrtz(s1[12], s1[13]), pD1 = pkrtz(s1[14], s1[15]);
            unsigned w0, w1, w2, w3, u0, u1, u2, u3;
            swap32(pA0, pB0, hi32, w0, w2);
            swap32(pA1, pB1, hi32, w1, w3);
            swap32(pC0, pD0, hi32, u0, u2);
            swap32(pC1, pD1, hi32, u1, u3);
            union { unsigned u[4]; half8 h; } f0, f1;
            f0.u[0] = w0; f0.u[1] = w1; f0.u[2] = w2; f0.u[3] = w3;  // k 32..47
            f1.u[0] = u0; f1.u[1] = u1; f1.u[2] = u2; f1.u[3] = u3;  // k 48..63
            __builtin_amdgcn_s_setprio(1);
            accO0 = MFMA32(f0.h, vf1[0][0], accO0);
            accO0 = MFMA32(f1.h, vf1[0][1], accO0);
            accO1 = MFMA32(f0.h, vf1[1][0], accO1);
            accO1 = MFMA32(f1.h, vf1[1][1], accO1);
            __builtin_amdgcn_s_setprio(0);
        }
    }

    // ---- k-split merge: wave1 publishes partials; wave0 merges + writes O ----
    if (wid == 1) {
        float* dst = &sM[lane * 35];
        dst[0] = mI;
        dst[1] = lI;
#pragma unroll
        for (int r = 0; r < 16; ++r) { dst[2 + r] = accO0[r]; dst[18 + r] = accO1[r]; }
    }
    __syncthreads();
    if (wid == 0) {
        const float* src = &sM[lane * 35];
        float m1 = src[0], l1 = src[1];
        float mstar = fmaxf(mI, m1);
        float sc0 = exp2_hw(mI - mstar);
        float sc1 = exp2_hw(m1 - mstar);
        float lt = lI * sc0 + l1 * sc1;
        float inv = 1.0f / lt;
        float f0 = sc0 * inv, f1 = sc1 * inv;   // per q-row (lane l31, both halves agree)
#pragma unroll
        for (int r = 0; r < 16; ++r) {
            int crow = (r & 3) + ((r >> 2) << 3) + (hi32 << 2);
            float fb0 = bperm_f(crow, f0);
            float fb1 = bperm_f(crow, f1);
            float o0 = accO0[r] * fb0 + src[2 + r] * fb1;
            float o1 = accO1[r] * fb0 + src[18 + r] * fb1;
            int qrow = q0 + crow;
            size_t base = ((size_t)(b * 4096 + qrow)) * 768 + h * 64;
            Ow[base + l31] = f2h_bits(o0);
            Ow[base + 32 + l31] = f2h_bits(o1);
        }
    }
}

// ---------------------------------------------------------------- launch
extern "C" void kernel_launch(void* const* d_in, const int* in_sizes, int n_in,
                              void* d_out, int out_size, void* d_ws, size_t ws_size,
                              hipStream_t stream) {
    const float* x = (const float*)d_in[0];
    const float* wkqv = (const float*)d_in[1];
    const float* wproj = (const float*)d_in[2];
    const float* bproj = (const float*)d_in[3];
    float* out = (float*)d_out;

    char* ws = (char*)d_ws;
    // layout (bytes): xb 12582912 | wkqvT 3538944 | wprojB 1179648 | Q 12582912 | K 12582912 | Vt 12582912
    unsigned short* xb = (unsigned short*)(ws);
    unsigned short* wkqvT = (unsigned short*)(ws + 12582912);
    unsigned short* wprojB = (unsigned short*)(ws + 16121856);
    unsigned short* Qw = (unsigned short*)(ws + 17301504);
    unsigned short* Kw = (unsigned short*)(ws + 29884416);
    unsigned short* Vtw = (unsigned short*)(ws + 42467328);
    unsigned short* Ow = xb;  // xb dead after KQV GEMM; reuse for attention output
    if (ws_size < 55050240) return;

    conv_all_kernel<<<13632, 256, 0, stream>>>(x, xb, wkqv, wkqvT, wproj, wprojB);
    gemm_bt_kernel<0, 128><<<64 * 18, 256, 0, stream>>>(xb, wkqvT, Qw, Kw, Vtw, nullptr, nullptr, 18);
    attn_kernel<<<24 * 128, 128, 0, stream>>>(Qw, Kw, Vtw, Ow);
    gemm_bt_kernel<1, 64><<<128 * 6, 128, 0, stream>>>(Ow, wprojB, nullptr, nullptr, nullptr, out, bproj, 6);
}